// Round 4
// baseline (650.456 us; speedup 1.0000x reference)
//
#include <hip/hip_runtime.h>
#include <hip/hip_bf16.h>

#define NNODES 50000
#define NEDGES 800000
#define NFEAT  512
#define NHID   64
#define NCLASS 40

#define SCAN_CHUNK 1024
#define SCAN_BLOCKS ((NNODES + SCAN_CHUNK - 1) / SCAN_CHUNK)   // 49

// ===========================================================================
// CSR build
// ===========================================================================
__global__ __launch_bounds__(256) void hist_kernel(
    const int* __restrict__ row, int* __restrict__ deg) {
    const int e = blockIdx.x * 256 + threadIdx.x;
    if (e < NEDGES) atomicAdd(&deg[row[e]], 1);
}

__global__ __launch_bounds__(256) void scan1_kernel(
    const int* __restrict__ deg, int* __restrict__ row_start,
    int* __restrict__ bsum) {
    __shared__ int lds[256];
    const int t = threadIdx.x;
    const int base = blockIdx.x * SCAN_CHUNK + t * 4;
    int d0 = 0, d1 = 0, d2 = 0, d3 = 0;
    if (base + 0 < NNODES) d0 = deg[base + 0];
    if (base + 1 < NNODES) d1 = deg[base + 1];
    if (base + 2 < NNODES) d2 = deg[base + 2];
    if (base + 3 < NNODES) d3 = deg[base + 3];
    const int s = d0 + d1 + d2 + d3;
    lds[t] = s;
    __syncthreads();
    for (int o = 1; o < 256; o <<= 1) {
        int v = lds[t];
        if (t >= o) v += lds[t - o];
        __syncthreads();
        lds[t] = v;
        __syncthreads();
    }
    int p = lds[t] - s;
    if (base + 0 < NNODES) row_start[base + 0] = p;
    if (base + 1 < NNODES) row_start[base + 1] = p + d0;
    if (base + 2 < NNODES) row_start[base + 2] = p + d0 + d1;
    if (base + 3 < NNODES) row_start[base + 3] = p + d0 + d1 + d2;
    if (t == 255) bsum[blockIdx.x] = lds[255];
}

__global__ __launch_bounds__(64) void scan2_kernel(int* __restrict__ bsum) {
    const int t = threadIdx.x;
    const int orig = (t < SCAN_BLOCKS) ? bsum[t] : 0;
    int v = orig;
    for (int o = 1; o < 64; o <<= 1) {
        const int u = __shfl_up(v, o);
        if (t >= o) v += u;
    }
    bsum[t] = v - orig;
}

__global__ __launch_bounds__(256) void scan3_kernel(
    int* __restrict__ row_start, const int* __restrict__ bsum,
    int* __restrict__ cursor) {
    const int i = blockIdx.x * 256 + threadIdx.x;
    if (i < NNODES) {
        const int v = row_start[i] + bsum[i / SCAN_CHUNK];
        row_start[i] = v;
        cursor[i] = v;
    }
    if (i == 0) row_start[NNODES] = NEDGES;
}

__global__ __launch_bounds__(256) void scatter_kernel(
    const int* __restrict__ row, const int* __restrict__ col,
    const float* __restrict__ ew, int* __restrict__ cursor,
    int2* __restrict__ edges) {
    const int e = blockIdx.x * 256 + threadIdx.x;
    if (e >= NEDGES) return;
    const int pos = atomicAdd(&cursor[row[e]], 1);
    edges[pos] = make_int2(col[e], __float_as_int(ew[e]));
}

// ===========================================================================
// GEMM1: out = x(50000x512) @ W(512x64) + b.  Register-resident W, no LDS
// in the main loop. Block = 4 waves; wave w owns K-slice [w*128, w*128+128),
// lane = output column, wreg[128] = W[k0+j][lane]. x rows are wave-uniform
// broadcast float4 loads (one L1 transaction). Partials from the 4 waves are
// combined via an 8 KB LDS reduction every 8 rows.
// ===========================================================================
__global__ __launch_bounds__(256) void gemm1_reg_kernel(
    const float* __restrict__ x, const float* __restrict__ W,
    const float* __restrict__ b, float* __restrict__ out) {
    __shared__ float red[4][8][64];          // 8 KB

    const int tid  = threadIdx.x;
    const int lane = tid & 63;
    const int wid  = __builtin_amdgcn_readfirstlane(tid >> 6);
    const int r0   = blockIdx.x * 64;

    // Load this wave's K-slice of W: 128 coalesced dword loads.
    float wreg[128];
    {
        const float* Wp = W + (size_t)(wid * 128) * NHID + lane;
        #pragma unroll
        for (int j = 0; j < 128; ++j) wreg[j] = Wp[(size_t)j * NHID];
    }

    for (int rb = 0; rb < 64; rb += 8) {
        float acc[8];
        #pragma unroll
        for (int rr = 0; rr < 8; ++rr) {
            const int r = r0 + rb + rr;
            float a0 = 0.f, a1 = 0.f;
            if (r < NNODES) {
                const float* xp = x + (size_t)r * NFEAT + wid * 128;
                #pragma unroll
                for (int j = 0; j < 128; j += 4) {
                    const float4 xv = *(const float4*)(xp + j);
                    a0 += xv.x * wreg[j + 0];
                    a1 += xv.y * wreg[j + 1];
                    a0 += xv.z * wreg[j + 2];
                    a1 += xv.w * wreg[j + 3];
                }
            }
            acc[rr] = a0 + a1;
        }
        #pragma unroll
        for (int rr = 0; rr < 8; ++rr) red[wid][rr][lane] = acc[rr];
        __syncthreads();
        #pragma unroll
        for (int t = 0; t < 2; ++t) {
            const int idx = tid + t * 256;          // 512 outputs: 8 rows x 64
            const int rr = idx >> 6, c = idx & 63;
            const int r = r0 + rb + rr;
            const float s = red[0][rr][c] + red[1][rr][c] +
                            red[2][rr][c] + red[3][rr][c] + b[c];
            if (r < NNODES) out[(size_t)r * NHID + c] = s;
        }
        __syncthreads();
    }
}

// ===========================================================================
// GEMM2: out = h(50000x64) @ W(64x64) + b.  Whole W column in 64 VGPRs;
// each wave handles 16 rows independently; no LDS anywhere.
// (ReLU already applied when h1 was written by spmm.)
// ===========================================================================
__global__ __launch_bounds__(256) void gemm2_reg_kernel(
    const float* __restrict__ h, const float* __restrict__ W,
    const float* __restrict__ b, float* __restrict__ out) {
    const int tid  = threadIdx.x;
    const int lane = tid & 63;
    const int wid  = __builtin_amdgcn_readfirstlane(tid >> 6);

    float wreg[64];
    #pragma unroll
    for (int j = 0; j < 64; ++j) wreg[j] = W[(size_t)j * NHID + lane];
    const float bias = b[lane];

    const int rbase = blockIdx.x * 64 + wid * 16;
    for (int i = 0; i < 16; ++i) {
        const int r = rbase + i;
        if (r >= NNODES) return;
        const float* hp = h + (size_t)r * NHID;
        float a0 = 0.f, a1 = 0.f;
        #pragma unroll
        for (int j = 0; j < 64; j += 4) {
            const float4 hv = *(const float4*)(hp + j);
            a0 += hv.x * wreg[j + 0];
            a1 += hv.y * wreg[j + 1];
            a0 += hv.z * wreg[j + 2];
            a1 += hv.w * wreg[j + 3];
        }
        out[(size_t)r * NHID + lane] = a0 + a1 + bias;
    }
}

// ===========================================================================
// GEMM3: out = h(50000x64) @ W(64x40) + b.  Lanes 0..39 hold W columns.
// ===========================================================================
__global__ __launch_bounds__(256) void gemm3_reg_kernel(
    const float* __restrict__ h, const float* __restrict__ W,
    const float* __restrict__ b, float* __restrict__ out) {
    const int tid  = threadIdx.x;
    const int lane = tid & 63;
    const int wid  = __builtin_amdgcn_readfirstlane(tid >> 6);
    const bool act = lane < NCLASS;

    float wreg[64];
    #pragma unroll
    for (int j = 0; j < 64; ++j)
        wreg[j] = act ? W[(size_t)j * NCLASS + lane] : 0.f;
    const float bias = act ? b[lane] : 0.f;

    const int rbase = blockIdx.x * 64 + wid * 16;
    for (int i = 0; i < 16; ++i) {
        const int r = rbase + i;
        if (r >= NNODES) return;
        const float* hp = h + (size_t)r * NHID;
        float a0 = 0.f, a1 = 0.f;
        #pragma unroll
        for (int j = 0; j < 64; j += 4) {
            const float4 hv = *(const float4*)(hp + j);
            a0 += hv.x * wreg[j + 0];
            a1 += hv.y * wreg[j + 1];
            a0 += hv.z * wreg[j + 2];
            a1 += hv.w * wreg[j + 3];
        }
        if (act) out[(size_t)r * NCLASS + lane] = a0 + a1 + bias;
    }
}

// ===========================================================================
// CSR SpMM, 64 feats: wave per node, lane = feature. Optional fused ReLU.
// ===========================================================================
template<bool RELU>
__global__ __launch_bounds__(256) void spmm_csr64_kernel(
    const float* __restrict__ sup, const int2* __restrict__ edges,
    const int* __restrict__ row_start, float* __restrict__ out) {
    const int f = threadIdx.x & 63;
    const int n = blockIdx.x * 4 + (threadIdx.x >> 6);
    if (n >= NNODES) return;
    const int s = row_start[n];
    const int e = row_start[n + 1];
    float acc = 0.f;
    int i = s;
    for (; i + 1 < e; i += 2) {
        const int2 e0 = edges[i];
        const int2 e1 = edges[i + 1];
        const float v0 = sup[(size_t)e0.x * NHID + f];
        const float v1 = sup[(size_t)e1.x * NHID + f];
        acc += v0 * __int_as_float(e0.y);
        acc += v1 * __int_as_float(e1.y);
    }
    if (i < e) {
        const int2 e0 = edges[i];
        acc += sup[(size_t)e0.x * NHID + f] * __int_as_float(e0.y);
    }
    out[(size_t)n * NHID + f] = RELU ? fmaxf(acc, 0.f) : acc;
}

// ===========================================================================
// CSR SpMM, 40 feats, fused log_softmax.
// ===========================================================================
__global__ __launch_bounds__(256) void spmm_csr40_lsm_kernel(
    const float* __restrict__ sup, const int2* __restrict__ edges,
    const int* __restrict__ row_start, float* __restrict__ out) {
    const int f = threadIdx.x & 63;
    const int n = blockIdx.x * 4 + (threadIdx.x >> 6);
    if (n >= NNODES) return;
    const int s = row_start[n];
    const int e = row_start[n + 1];
    float acc = 0.f;
    if (f < NCLASS) {
        int i = s;
        for (; i + 1 < e; i += 2) {
            const int2 e0 = edges[i];
            const int2 e1 = edges[i + 1];
            const float v0 = sup[(size_t)e0.x * NCLASS + f];
            const float v1 = sup[(size_t)e1.x * NCLASS + f];
            acc += v0 * __int_as_float(e0.y);
            acc += v1 * __int_as_float(e1.y);
        }
        if (i < e) {
            const int2 e0 = edges[i];
            acc += sup[(size_t)e0.x * NCLASS + f] * __int_as_float(e0.y);
        }
    }
    float m = (f < NCLASS) ? acc : -1e30f;
    #pragma unroll
    for (int o = 32; o > 0; o >>= 1) m = fmaxf(m, __shfl_xor(m, o));
    float ex = (f < NCLASS) ? __expf(acc - m) : 0.f;
    #pragma unroll
    for (int o = 32; o > 0; o >>= 1) ex += __shfl_xor(ex, o);
    const float ls = __logf(ex) + m;
    if (f < NCLASS) out[(size_t)n * NCLASS + f] = acc - ls;
}

// ===========================================================================
extern "C" void kernel_launch(void* const* d_in, const int* in_sizes, int n_in,
                              void* d_out, int out_size, void* d_ws, size_t ws_size,
                              hipStream_t stream) {
    const float* x  = (const float*)d_in[0];
    const float* ew = (const float*)d_in[1];
    const float* W1 = (const float*)d_in[2];
    const float* b1 = (const float*)d_in[3];
    const float* W2 = (const float*)d_in[4];
    const float* b2 = (const float*)d_in[5];
    const float* W3 = (const float*)d_in[6];
    const float* b3 = (const float*)d_in[7];
    const int* row  = (const int*)d_in[8];
    const int* col  = (const int*)d_in[9];
    float* out = (float*)d_out;

    const size_t n64 = (size_t)NNODES * NHID;
    float* A = (float*)d_ws;                  // support1 / support2 / support3
    float* B = A + n64;                       // h1 / h2
    int* deg       = (int*)(B + n64);
    int* cursor    = deg + NNODES;
    int* row_start = cursor + NNODES;
    int* bsum      = row_start + NNODES + 2;
    int2* edges    = (int2*)(bsum + 64);

    const int rowBlocks  = (NNODES + 63) / 64;    // 782
    const int nodeBlocks = (NNODES + 3) / 4;
    const int edgeBlocks = (NEDGES + 255) / 256;

    // ---- CSR build ----
    hipMemsetAsync(deg, 0, NNODES * sizeof(int), stream);
    hist_kernel<<<edgeBlocks, 256, 0, stream>>>(row, deg);
    scan1_kernel<<<SCAN_BLOCKS, 256, 0, stream>>>(deg, row_start, bsum);
    scan2_kernel<<<1, 64, 0, stream>>>(bsum);
    scan3_kernel<<<(NNODES + 255) / 256, 256, 0, stream>>>(row_start, bsum, cursor);
    scatter_kernel<<<edgeBlocks, 256, 0, stream>>>(row, col, ew, cursor, edges);

    // ---- Layer 1 (ReLU fused into spmm write) ----
    gemm1_reg_kernel<<<rowBlocks, 256, 0, stream>>>(x, W1, b1, A);
    spmm_csr64_kernel<true><<<nodeBlocks, 256, 0, stream>>>(A, edges, row_start, B);

    // ---- Layer 2 ----
    gemm2_reg_kernel<<<rowBlocks, 256, 0, stream>>>(B, W2, b2, A);
    spmm_csr64_kernel<false><<<nodeBlocks, 256, 0, stream>>>(A, edges, row_start, B);

    // ---- Layer 3 (SpMM + log_softmax fused -> d_out) ----
    gemm3_reg_kernel<<<rowBlocks, 256, 0, stream>>>(B, W3, b3, A);
    spmm_csr40_lsm_kernel<<<nodeBlocks, 256, 0, stream>>>(A, edges, row_start, out);
}

// Round 5
// 486.228 us; speedup vs baseline: 1.3378x; 1.3378x over previous
//
#include <hip/hip_runtime.h>
#include <hip/hip_bf16.h>

#define NNODES 50000
#define NEDGES 800000
#define NFEAT  512
#define NHID   64
#define NCLASS 40

#define SCAN_CHUNK 1024
#define SCAN_BLOCKS ((NNODES + SCAN_CHUNK - 1) / SCAN_CHUNK)   // 49

typedef __attribute__((ext_vector_type(8))) short short8;
typedef __attribute__((ext_vector_type(4))) float floatx4;

// fp32 -> bf16 with round-to-nearest-even
static __device__ __forceinline__ short f2bf(float f) {
    union { float f; unsigned u; } v; v.f = f;
    const unsigned r = v.u + 0x7fffu + ((v.u >> 16) & 1u);
    return (short)(r >> 16);
}

// ===========================================================================
// CSR build
// ===========================================================================
__global__ __launch_bounds__(256) void hist_kernel(
    const int* __restrict__ row, int* __restrict__ deg) {
    const int e = blockIdx.x * 256 + threadIdx.x;
    if (e < NEDGES) atomicAdd(&deg[row[e]], 1);
}

__global__ __launch_bounds__(256) void scan1_kernel(
    const int* __restrict__ deg, int* __restrict__ row_start,
    int* __restrict__ bsum) {
    __shared__ int lds[256];
    const int t = threadIdx.x;
    const int base = blockIdx.x * SCAN_CHUNK + t * 4;
    int d0 = 0, d1 = 0, d2 = 0, d3 = 0;
    if (base + 0 < NNODES) d0 = deg[base + 0];
    if (base + 1 < NNODES) d1 = deg[base + 1];
    if (base + 2 < NNODES) d2 = deg[base + 2];
    if (base + 3 < NNODES) d3 = deg[base + 3];
    const int s = d0 + d1 + d2 + d3;
    lds[t] = s;
    __syncthreads();
    for (int o = 1; o < 256; o <<= 1) {
        int v = lds[t];
        if (t >= o) v += lds[t - o];
        __syncthreads();
        lds[t] = v;
        __syncthreads();
    }
    int p = lds[t] - s;
    if (base + 0 < NNODES) row_start[base + 0] = p;
    if (base + 1 < NNODES) row_start[base + 1] = p + d0;
    if (base + 2 < NNODES) row_start[base + 2] = p + d0 + d1;
    if (base + 3 < NNODES) row_start[base + 3] = p + d0 + d1 + d2;
    if (t == 255) bsum[blockIdx.x] = lds[255];
}

__global__ __launch_bounds__(64) void scan2_kernel(int* __restrict__ bsum) {
    const int t = threadIdx.x;
    const int orig = (t < SCAN_BLOCKS) ? bsum[t] : 0;
    int v = orig;
    for (int o = 1; o < 64; o <<= 1) {
        const int u = __shfl_up(v, o);
        if (t >= o) v += u;
    }
    bsum[t] = v - orig;
}

__global__ __launch_bounds__(256) void scan3_kernel(
    int* __restrict__ row_start, const int* __restrict__ bsum,
    int* __restrict__ cursor) {
    const int i = blockIdx.x * 256 + threadIdx.x;
    if (i < NNODES) {
        const int v = row_start[i] + bsum[i / SCAN_CHUNK];
        row_start[i] = v;
        cursor[i] = v;
    }
    if (i == 0) row_start[NNODES] = NEDGES;
}

__global__ __launch_bounds__(256) void scatter_kernel(
    const int* __restrict__ row, const int* __restrict__ col,
    const float* __restrict__ ew, int* __restrict__ cursor,
    int2* __restrict__ edges) {
    const int e = blockIdx.x * 256 + threadIdx.x;
    if (e >= NEDGES) return;
    const int pos = atomicAdd(&cursor[row[e]], 1);
    edges[pos] = make_int2(col[e], __float_as_int(ew[e]));
}

// ===========================================================================
// W1 (512x64 fp32) -> bf16, B-fragment layout for mfma_f32_16x16x32_bf16:
// wb[((kb*4 + cb)*64 + lane)*8 + j] = bf16( W[(kb*32 + 8*(lane>>4) + j)*64
//                                             + cb*16 + (lane&15)] )
// so in gemm1 each lane's 8 B-values are one contiguous 16 B load, and the
// wave's 64 loads are a fully-coalesced 1 KB.
// ===========================================================================
__global__ __launch_bounds__(256) void convW1_kernel(
    const float* __restrict__ W, short* __restrict__ wb) {
    const int idx = blockIdx.x * 256 + threadIdx.x;   // 0..4095
    if (idx >= 16 * 4 * 64) return;
    const int lane = idx & 63;
    const int cb   = (idx >> 6) & 3;
    const int kb   = idx >> 8;
    const int q = lane >> 4, m = lane & 15;
    short8 v;
    #pragma unroll
    for (int j = 0; j < 8; ++j)
        v[j] = f2bf(W[(size_t)(kb * 32 + q * 8 + j) * NHID + cb * 16 + m]);
    *(short8*)(wb + (size_t)idx * 8) = v;
}

// ===========================================================================
// GEMM1 via MFMA: out = x(50000x512) @ W1(512x64) + b1,  bf16 inputs.
// Block = 4 waves; wave w owns rows [blk*64 + w*16, +16).
// A-frag: lane reads 8 consecutive fp32 of its row (rows x k-quads cover a
// full 128 B L2 line per row per k-step), converts to bf16 in-register.
// B-frag: coalesced 16 B loads from the pre-converted wb (64 KB, L2-hot).
// No LDS. acc: 4 col-blocks x float4 (C/D layout: col=lane&15,
// row=(lane>>4)*4+i  [m89-verified]).
// ===========================================================================
__global__ __launch_bounds__(256) void gemm1_mfma_kernel(
    const float* __restrict__ x, const short* __restrict__ wb,
    const float* __restrict__ b, float* __restrict__ out) {
    const int tid  = threadIdx.x;
    const int lane = tid & 63;
    const int wid  = tid >> 6;
    const int q = lane >> 4, m = lane & 15;

    const int rowbase = blockIdx.x * 64 + wid * 16;
    int rload = rowbase + m;
    if (rload >= NNODES) rload = NNODES - 1;       // clamp: M-rows independent
    const float* xp = x + (size_t)rload * NFEAT + q * 8;

    floatx4 acc[4];
    #pragma unroll
    for (int cb = 0; cb < 4; ++cb) acc[cb] = (floatx4)0.f;

    for (int kb = 0; kb < 16; ++kb) {
        const float4 a0 = *(const float4*)(xp + kb * 32);
        const float4 a1 = *(const float4*)(xp + kb * 32 + 4);
        short8 afrag;
        afrag[0] = f2bf(a0.x); afrag[1] = f2bf(a0.y);
        afrag[2] = f2bf(a0.z); afrag[3] = f2bf(a0.w);
        afrag[4] = f2bf(a1.x); afrag[5] = f2bf(a1.y);
        afrag[6] = f2bf(a1.z); afrag[7] = f2bf(a1.w);

        const short* wp = wb + ((size_t)(kb * 4) * 64 + lane) * 8;
        #pragma unroll
        for (int cb = 0; cb < 4; ++cb) {
            const short8 bfrag = *(const short8*)(wp + (size_t)cb * 64 * 8);
            acc[cb] = __builtin_amdgcn_mfma_f32_16x16x32_bf16(
                afrag, bfrag, acc[cb], 0, 0, 0);
        }
    }

    // Epilogue: C/D layout col = m, row = q*4 + i (within the 16x16 tile).
    const int orow = rowbase + q * 4;
    #pragma unroll
    for (int cb = 0; cb < 4; ++cb) {
        const int c = cb * 16 + m;
        const float bias = b[c];
        #pragma unroll
        for (int i = 0; i < 4; ++i) {
            const int r = orow + i;
            if (r < NNODES) out[(size_t)r * NHID + c] = acc[cb][i] + bias;
        }
    }
}

// ===========================================================================
// GEMM2: out = h(50000x64) @ W(64x64) + b.  W column in 64 VGPRs.
// ===========================================================================
__global__ __launch_bounds__(256) void gemm2_reg_kernel(
    const float* __restrict__ h, const float* __restrict__ W,
    const float* __restrict__ b, float* __restrict__ out) {
    const int tid  = threadIdx.x;
    const int lane = tid & 63;
    const int wid  = __builtin_amdgcn_readfirstlane(tid >> 6);

    float wreg[64];
    #pragma unroll
    for (int j = 0; j < 64; ++j) wreg[j] = W[(size_t)j * NHID + lane];
    const float bias = b[lane];

    const int rbase = blockIdx.x * 64 + wid * 16;
    for (int i = 0; i < 16; ++i) {
        const int r = rbase + i;
        if (r >= NNODES) return;
        const float* hp = h + (size_t)r * NHID;
        float a0 = 0.f, a1 = 0.f;
        #pragma unroll
        for (int j = 0; j < 64; j += 4) {
            const float4 hv = *(const float4*)(hp + j);
            a0 += hv.x * wreg[j + 0];
            a1 += hv.y * wreg[j + 1];
            a0 += hv.z * wreg[j + 2];
            a1 += hv.w * wreg[j + 3];
        }
        out[(size_t)r * NHID + lane] = a0 + a1 + bias;
    }
}

// ===========================================================================
// GEMM3: out = h(50000x64) @ W(64x40) + b.  Lanes 0..39 hold W columns.
// ===========================================================================
__global__ __launch_bounds__(256) void gemm3_reg_kernel(
    const float* __restrict__ h, const float* __restrict__ W,
    const float* __restrict__ b, float* __restrict__ out) {
    const int tid  = threadIdx.x;
    const int lane = tid & 63;
    const int wid  = __builtin_amdgcn_readfirstlane(tid >> 6);
    const bool act = lane < NCLASS;

    float wreg[64];
    #pragma unroll
    for (int j = 0; j < 64; ++j)
        wreg[j] = act ? W[(size_t)j * NCLASS + lane] : 0.f;
    const float bias = act ? b[lane] : 0.f;

    const int rbase = blockIdx.x * 64 + wid * 16;
    for (int i = 0; i < 16; ++i) {
        const int r = rbase + i;
        if (r >= NNODES) return;
        const float* hp = h + (size_t)r * NHID;
        float a0 = 0.f, a1 = 0.f;
        #pragma unroll
        for (int j = 0; j < 64; j += 4) {
            const float4 hv = *(const float4*)(hp + j);
            a0 += hv.x * wreg[j + 0];
            a1 += hv.y * wreg[j + 1];
            a0 += hv.z * wreg[j + 2];
            a1 += hv.w * wreg[j + 3];
        }
        if (act) out[(size_t)r * NCLASS + lane] = a0 + a1 + bias;
    }
}

// ===========================================================================
// CSR SpMM, 64 feats: wave per node, lane = feature. Optional fused ReLU.
// ===========================================================================
template<bool RELU>
__global__ __launch_bounds__(256) void spmm_csr64_kernel(
    const float* __restrict__ sup, const int2* __restrict__ edges,
    const int* __restrict__ row_start, float* __restrict__ out) {
    const int f = threadIdx.x & 63;
    const int n = blockIdx.x * 4 + (threadIdx.x >> 6);
    if (n >= NNODES) return;
    const int s = row_start[n];
    const int e = row_start[n + 1];
    float acc = 0.f;
    int i = s;
    for (; i + 1 < e; i += 2) {
        const int2 e0 = edges[i];
        const int2 e1 = edges[i + 1];
        const float v0 = sup[(size_t)e0.x * NHID + f];
        const float v1 = sup[(size_t)e1.x * NHID + f];
        acc += v0 * __int_as_float(e0.y);
        acc += v1 * __int_as_float(e1.y);
    }
    if (i < e) {
        const int2 e0 = edges[i];
        acc += sup[(size_t)e0.x * NHID + f] * __int_as_float(e0.y);
    }
    out[(size_t)n * NHID + f] = RELU ? fmaxf(acc, 0.f) : acc;
}

// ===========================================================================
// CSR SpMM, 40 feats, fused log_softmax.
// ===========================================================================
__global__ __launch_bounds__(256) void spmm_csr40_lsm_kernel(
    const float* __restrict__ sup, const int2* __restrict__ edges,
    const int* __restrict__ row_start, float* __restrict__ out) {
    const int f = threadIdx.x & 63;
    const int n = blockIdx.x * 4 + (threadIdx.x >> 6);
    if (n >= NNODES) return;
    const int s = row_start[n];
    const int e = row_start[n + 1];
    float acc = 0.f;
    if (f < NCLASS) {
        int i = s;
        for (; i + 1 < e; i += 2) {
            const int2 e0 = edges[i];
            const int2 e1 = edges[i + 1];
            const float v0 = sup[(size_t)e0.x * NCLASS + f];
            const float v1 = sup[(size_t)e1.x * NCLASS + f];
            acc += v0 * __int_as_float(e0.y);
            acc += v1 * __int_as_float(e1.y);
        }
        if (i < e) {
            const int2 e0 = edges[i];
            acc += sup[(size_t)e0.x * NCLASS + f] * __int_as_float(e0.y);
        }
    }
    float m = (f < NCLASS) ? acc : -1e30f;
    #pragma unroll
    for (int o = 32; o > 0; o >>= 1) m = fmaxf(m, __shfl_xor(m, o));
    float ex = (f < NCLASS) ? __expf(acc - m) : 0.f;
    #pragma unroll
    for (int o = 32; o > 0; o >>= 1) ex += __shfl_xor(ex, o);
    const float ls = __logf(ex) + m;
    if (f < NCLASS) out[(size_t)n * NCLASS + f] = acc - ls;
}

// ===========================================================================
extern "C" void kernel_launch(void* const* d_in, const int* in_sizes, int n_in,
                              void* d_out, int out_size, void* d_ws, size_t ws_size,
                              hipStream_t stream) {
    const float* x  = (const float*)d_in[0];
    const float* ew = (const float*)d_in[1];
    const float* W1 = (const float*)d_in[2];
    const float* b1 = (const float*)d_in[3];
    const float* W2 = (const float*)d_in[4];
    const float* b2 = (const float*)d_in[5];
    const float* W3 = (const float*)d_in[6];
    const float* b3 = (const float*)d_in[7];
    const int* row  = (const int*)d_in[8];
    const int* col  = (const int*)d_in[9];
    float* out = (float*)d_out;

    const size_t n64 = (size_t)NNODES * NHID;
    float* A = (float*)d_ws;                  // support1 / support2 / support3
    float* B = A + n64;                       // h1 / h2
    int* deg       = (int*)(B + n64);
    int* cursor    = deg + NNODES;
    int* row_start = cursor + NNODES;
    int* bsum      = row_start + NNODES + 2;
    int2* edges    = (int2*)(bsum + 64);      // NEDGES int2
    short* wb      = (short*)(edges + NEDGES);// 16*4*64*8 shorts = 64 KB

    const int rowBlocks  = (NNODES + 63) / 64;    // 782
    const int nodeBlocks = (NNODES + 3) / 4;
    const int edgeBlocks = (NEDGES + 255) / 256;

    // ---- CSR build + W1 conversion ----
    hipMemsetAsync(deg, 0, NNODES * sizeof(int), stream);
    convW1_kernel<<<16, 256, 0, stream>>>(W1, wb);
    hist_kernel<<<edgeBlocks, 256, 0, stream>>>(row, deg);
    scan1_kernel<<<SCAN_BLOCKS, 256, 0, stream>>>(deg, row_start, bsum);
    scan2_kernel<<<1, 64, 0, stream>>>(bsum);
    scan3_kernel<<<(NNODES + 255) / 256, 256, 0, stream>>>(row_start, bsum, cursor);
    scatter_kernel<<<edgeBlocks, 256, 0, stream>>>(row, col, ew, cursor, edges);

    // ---- Layer 1 (MFMA gemm; ReLU fused into spmm write) ----
    gemm1_mfma_kernel<<<rowBlocks, 256, 0, stream>>>(x, wb, b1, A);
    spmm_csr64_kernel<true><<<nodeBlocks, 256, 0, stream>>>(A, edges, row_start, B);

    // ---- Layer 2 ----
    gemm2_reg_kernel<<<rowBlocks, 256, 0, stream>>>(B, W2, b2, A);
    spmm_csr64_kernel<false><<<nodeBlocks, 256, 0, stream>>>(A, edges, row_start, B);

    // ---- Layer 3 (SpMM + log_softmax fused -> d_out) ----
    gemm3_reg_kernel<<<rowBlocks, 256, 0, stream>>>(B, W3, b3, A);
    spmm_csr40_lsm_kernel<<<nodeBlocks, 256, 0, stream>>>(A, edges, row_start, out);
}

// Round 6
// 407.302 us; speedup vs baseline: 1.5970x; 1.1938x over previous
//
#include <hip/hip_runtime.h>
#include <hip/hip_bf16.h>

#define NNODES 50000
#define NEDGES 800000
#define NFEAT  512
#define NHID   64
#define NCLASS 40

#define SCAN_CHUNK 1024
#define SCAN_BLOCKS ((NNODES + SCAN_CHUNK - 1) / SCAN_CHUNK)   // 49

typedef __attribute__((ext_vector_type(8))) short short8;
typedef __attribute__((ext_vector_type(4))) float floatx4;

// fp32 -> bf16 (RNE)
static __device__ __forceinline__ unsigned short f2bf(float f) {
    union { float f; unsigned u; } v; v.f = f;
    const unsigned r = v.u + 0x7fffu + ((v.u >> 16) & 1u);
    return (unsigned short)(r >> 16);
}
static __device__ __forceinline__ float bf2f(unsigned u) {
    union { unsigned u; float f; } v; v.u = u << 16;
    return v.f;
}

// ===========================================================================
// CSR build
// ===========================================================================
__global__ __launch_bounds__(256) void hist_kernel(
    const int* __restrict__ row, int* __restrict__ deg) {
    const int e = blockIdx.x * 256 + threadIdx.x;
    if (e < NEDGES) atomicAdd(&deg[row[e]], 1);
}

__global__ __launch_bounds__(256) void scan1_kernel(
    const int* __restrict__ deg, int* __restrict__ row_start,
    int* __restrict__ bsum) {
    __shared__ int lds[256];
    const int t = threadIdx.x;
    const int base = blockIdx.x * SCAN_CHUNK + t * 4;
    int d0 = 0, d1 = 0, d2 = 0, d3 = 0;
    if (base + 0 < NNODES) d0 = deg[base + 0];
    if (base + 1 < NNODES) d1 = deg[base + 1];
    if (base + 2 < NNODES) d2 = deg[base + 2];
    if (base + 3 < NNODES) d3 = deg[base + 3];
    const int s = d0 + d1 + d2 + d3;
    lds[t] = s;
    __syncthreads();
    for (int o = 1; o < 256; o <<= 1) {
        int v = lds[t];
        if (t >= o) v += lds[t - o];
        __syncthreads();
        lds[t] = v;
        __syncthreads();
    }
    int p = lds[t] - s;
    if (base + 0 < NNODES) row_start[base + 0] = p;
    if (base + 1 < NNODES) row_start[base + 1] = p + d0;
    if (base + 2 < NNODES) row_start[base + 2] = p + d0 + d1;
    if (base + 3 < NNODES) row_start[base + 3] = p + d0 + d1 + d2;
    if (t == 255) bsum[blockIdx.x] = lds[255];
}

__global__ __launch_bounds__(64) void scan2_kernel(int* __restrict__ bsum) {
    const int t = threadIdx.x;
    const int orig = (t < SCAN_BLOCKS) ? bsum[t] : 0;
    int v = orig;
    for (int o = 1; o < 64; o <<= 1) {
        const int u = __shfl_up(v, o);
        if (t >= o) v += u;
    }
    bsum[t] = v - orig;
}

__global__ __launch_bounds__(256) void scan3_kernel(
    int* __restrict__ row_start, const int* __restrict__ bsum,
    int* __restrict__ cursor) {
    const int i = blockIdx.x * 256 + threadIdx.x;
    if (i < NNODES) {
        const int v = row_start[i] + bsum[i / SCAN_CHUNK];
        row_start[i] = v;
        cursor[i] = v;
    }
    if (i == 0) row_start[NNODES] = NEDGES;
}

__global__ __launch_bounds__(256) void scatter_kernel(
    const int* __restrict__ row, const int* __restrict__ col,
    const float* __restrict__ ew, int* __restrict__ cursor,
    int2* __restrict__ edges) {
    const int e = blockIdx.x * 256 + threadIdx.x;
    if (e >= NEDGES) return;
    const int pos = atomicAdd(&cursor[row[e]], 1);
    edges[pos] = make_int2(col[e], __float_as_int(ew[e]));
}

// ===========================================================================
// Weight conversion to MFMA B-fragment layout (bf16).
// wb[((kb*NCB + cb)*64 + lane)*8 + j] = bf16(W[(kb*32 + (lane>>4)*8 + j)*N
//                                              + cb*16 + (lane&15)])
// ===========================================================================
template<int KB, int NCB, int N, int NVALID>
__global__ __launch_bounds__(256) void convW_kernel(
    const float* __restrict__ W, unsigned short* __restrict__ wb) {
    const int idx = blockIdx.x * 256 + threadIdx.x;
    if (idx >= KB * NCB * 64) return;
    const int lane = idx & 63;
    const int cb   = (idx >> 6) % NCB;
    const int kb   = idx / (64 * NCB);
    const int q = lane >> 4, m = lane & 15;
    const int c = cb * 16 + m;
    short8 v;
    #pragma unroll
    for (int j = 0; j < 8; ++j)
        v[j] = (c < NVALID)
             ? (short)f2bf(W[(size_t)(kb * 32 + q * 8 + j) * NVALID + c])
             : (short)0;
    *(short8*)(wb + (size_t)idx * 8) = v;
}

// ===========================================================================
// GEMM1 via MFMA: Ab(bf16) = x(50000x512 fp32) @ W1 + b1.
// A-frag converted in-register from fp32 x; B-frag from pre-converted wb.
// ===========================================================================
__global__ __launch_bounds__(256) void gemm1_mfma_kernel(
    const float* __restrict__ x, const unsigned short* __restrict__ wb,
    const float* __restrict__ b, unsigned short* __restrict__ outb) {
    const int tid  = threadIdx.x;
    const int lane = tid & 63;
    const int wid  = tid >> 6;
    const int q = lane >> 4, m = lane & 15;

    const int rowbase = blockIdx.x * 64 + wid * 16;
    int rload = rowbase + m;
    if (rload >= NNODES) rload = NNODES - 1;
    const float* xp = x + (size_t)rload * NFEAT + q * 8;

    floatx4 acc[4];
    #pragma unroll
    for (int cb = 0; cb < 4; ++cb) acc[cb] = (floatx4)0.f;

    for (int kb = 0; kb < 16; ++kb) {
        const float4 a0 = *(const float4*)(xp + kb * 32);
        const float4 a1 = *(const float4*)(xp + kb * 32 + 4);
        short8 afrag;
        afrag[0] = (short)f2bf(a0.x); afrag[1] = (short)f2bf(a0.y);
        afrag[2] = (short)f2bf(a0.z); afrag[3] = (short)f2bf(a0.w);
        afrag[4] = (short)f2bf(a1.x); afrag[5] = (short)f2bf(a1.y);
        afrag[6] = (short)f2bf(a1.z); afrag[7] = (short)f2bf(a1.w);

        const unsigned short* wp = wb + ((size_t)(kb * 4) * 64 + lane) * 8;
        #pragma unroll
        for (int cb = 0; cb < 4; ++cb) {
            const short8 bfrag = *(const short8*)(wp + (size_t)cb * 64 * 8);
            acc[cb] = __builtin_amdgcn_mfma_f32_16x16x32_bf16(
                afrag, bfrag, acc[cb], 0, 0, 0);
        }
    }

    const int orow = rowbase + q * 4;
    #pragma unroll
    for (int cb = 0; cb < 4; ++cb) {
        const int c = cb * 16 + m;
        const float bias = b[c];
        #pragma unroll
        for (int i = 0; i < 4; ++i) {
            const int r = orow + i;
            if (r < NNODES)
                outb[(size_t)r * NHID + c] = f2bf(acc[cb][i] + bias);
        }
    }
}

// ===========================================================================
// GEMM2/3 via MFMA: outb(bf16) = h(bf16, 50000x64) @ W + b.
// A-frag is a DIRECT 16B load from bf16 h. NCB col-tiles (4 for N=64,
// 3 for N=48-padded-40). NOUT = stored row width (64 or 40).
// ===========================================================================
template<int NCB, int NOUT>
__global__ __launch_bounds__(256) void gemm_h_mfma_kernel(
    const unsigned short* __restrict__ hb, const unsigned short* __restrict__ wb,
    const float* __restrict__ b, unsigned short* __restrict__ outb) {
    const int tid  = threadIdx.x;
    const int lane = tid & 63;
    const int wid  = tid >> 6;
    const int q = lane >> 4, m = lane & 15;

    const int rowbase = blockIdx.x * 64 + wid * 16;
    int rload = rowbase + m;
    if (rload >= NNODES) rload = NNODES - 1;
    const unsigned short* hp = hb + (size_t)rload * NHID + q * 8;

    floatx4 acc[NCB];
    #pragma unroll
    for (int cb = 0; cb < NCB; ++cb) acc[cb] = (floatx4)0.f;

    #pragma unroll
    for (int kb = 0; kb < 2; ++kb) {
        const short8 afrag = *(const short8*)(hp + kb * 32);
        const unsigned short* wp = wb + ((size_t)(kb * NCB) * 64 + lane) * 8;
        #pragma unroll
        for (int cb = 0; cb < NCB; ++cb) {
            const short8 bfrag = *(const short8*)(wp + (size_t)cb * 64 * 8);
            acc[cb] = __builtin_amdgcn_mfma_f32_16x16x32_bf16(
                afrag, bfrag, acc[cb], 0, 0, 0);
        }
    }

    const int orow = rowbase + q * 4;
    #pragma unroll
    for (int cb = 0; cb < NCB; ++cb) {
        const int c = cb * 16 + m;
        if (c >= NOUT) continue;
        const float bias = b[c];
        #pragma unroll
        for (int i = 0; i < 4; ++i) {
            const int r = orow + i;
            if (r < NNODES)
                outb[(size_t)r * NOUT + c] = f2bf(acc[cb][i] + bias);
        }
    }
}

// ===========================================================================
// CSR SpMM, 64 bf16 feats: wave per node, HALF-WAVE per edge.
// Lane l: half = l>>5 picks edge parity, fp = l&31 picks feature pair
// (2 bf16 = one 4B load). Cross-half combine via shfl_xor(32).
// Gathered row = 128 B = one cache line. Optional fused ReLU.
// ===========================================================================
template<bool RELU>
__global__ __launch_bounds__(256) void spmm_bf64_kernel(
    const unsigned short* __restrict__ supb, const int2* __restrict__ edges,
    const int* __restrict__ row_start, unsigned short* __restrict__ outb) {
    const int lane = threadIdx.x & 63;
    const int n = blockIdx.x * 4 + (threadIdx.x >> 6);
    if (n >= NNODES) return;
    const int half = lane >> 5;
    const int fp   = lane & 31;
    const int s = row_start[n];
    const int e = row_start[n + 1];

    float a0 = 0.f, a1 = 0.f;
    int i = s + half;
    for (; i + 2 < e; i += 4) {                 // 2 edges per half per iter
        const int2 e0 = edges[i];
        const int2 e1 = edges[i + 2];
        const unsigned v0 = *(const unsigned*)(supb + (size_t)e0.x * NHID + fp * 2);
        const unsigned v1 = *(const unsigned*)(supb + (size_t)e1.x * NHID + fp * 2);
        const float w0 = __int_as_float(e0.y);
        const float w1 = __int_as_float(e1.y);
        a0 += w0 * bf2f(v0 & 0xffffu);
        a1 += w0 * bf2f(v0 >> 16);
        a0 += w1 * bf2f(v1 & 0xffffu);
        a1 += w1 * bf2f(v1 >> 16);
    }
    if (i < e) {
        const int2 e0 = edges[i];
        const unsigned v0 = *(const unsigned*)(supb + (size_t)e0.x * NHID + fp * 2);
        const float w0 = __int_as_float(e0.y);
        a0 += w0 * bf2f(v0 & 0xffffu);
        a1 += w0 * bf2f(v0 >> 16);
    }
    a0 += __shfl_xor(a0, 32);
    a1 += __shfl_xor(a1, 32);
    if (half == 0) {
        if (RELU) { a0 = fmaxf(a0, 0.f); a1 = fmaxf(a1, 0.f); }
        const unsigned packed = (unsigned)f2bf(a0) | ((unsigned)f2bf(a1) << 16);
        *(unsigned*)(outb + (size_t)n * NHID + fp * 2) = packed;
    }
}

// ===========================================================================
// CSR SpMM, 40 bf16 feats, fused log_softmax -> fp32 out.
// Wave per node, lane = feature (lanes 40..63 idle in loop).
// ===========================================================================
__global__ __launch_bounds__(256) void spmm_bf40_lsm_kernel(
    const unsigned short* __restrict__ supb, const int2* __restrict__ edges,
    const int* __restrict__ row_start, float* __restrict__ out) {
    const int f = threadIdx.x & 63;
    const int n = blockIdx.x * 4 + (threadIdx.x >> 6);
    if (n >= NNODES) return;
    const int s = row_start[n];
    const int e = row_start[n + 1];
    float acc = 0.f;
    if (f < NCLASS) {
        int i = s;
        for (; i + 1 < e; i += 2) {
            const int2 e0 = edges[i];
            const int2 e1 = edges[i + 1];
            const float v0 = bf2f(supb[(size_t)e0.x * NCLASS + f]);
            const float v1 = bf2f(supb[(size_t)e1.x * NCLASS + f]);
            acc += v0 * __int_as_float(e0.y);
            acc += v1 * __int_as_float(e1.y);
        }
        if (i < e) {
            const int2 e0 = edges[i];
            acc += bf2f(supb[(size_t)e0.x * NCLASS + f]) * __int_as_float(e0.y);
        }
    }
    float m = (f < NCLASS) ? acc : -1e30f;
    #pragma unroll
    for (int o = 32; o > 0; o >>= 1) m = fmaxf(m, __shfl_xor(m, o));
    float ex = (f < NCLASS) ? __expf(acc - m) : 0.f;
    #pragma unroll
    for (int o = 32; o > 0; o >>= 1) ex += __shfl_xor(ex, o);
    const float ls = __logf(ex) + m;
    if (f < NCLASS) out[(size_t)n * NCLASS + f] = acc - ls;
}

// ===========================================================================
extern "C" void kernel_launch(void* const* d_in, const int* in_sizes, int n_in,
                              void* d_out, int out_size, void* d_ws, size_t ws_size,
                              hipStream_t stream) {
    const float* x  = (const float*)d_in[0];
    const float* ew = (const float*)d_in[1];
    const float* W1 = (const float*)d_in[2];
    const float* b1 = (const float*)d_in[3];
    const float* W2 = (const float*)d_in[4];
    const float* b2 = (const float*)d_in[5];
    const float* W3 = (const float*)d_in[6];
    const float* b3 = (const float*)d_in[7];
    const int* row  = (const int*)d_in[8];
    const int* col  = (const int*)d_in[9];
    float* out = (float*)d_out;

    // Workspace layout (16B-aligned chunks):
    const size_t n64 = (size_t)NNODES * NHID;      // elements
    const size_t n40 = (size_t)NNODES * NCLASS;
    unsigned short* Ab = (unsigned short*)d_ws;    // support1/2 bf16 (6.4 MB)
    unsigned short* Bb = Ab + n64;                 // h1/h2 bf16     (6.4 MB)
    unsigned short* Cb = Bb + n64;                 // support3 bf16  (4.0 MB)
    unsigned short* wb1 = Cb + n40;                // 16*4*64*8 = 32768 (64 KB)
    unsigned short* wb2 = wb1 + 16 * 4 * 64 * 8;   // 2*4*64*8 = 4096  (8 KB)
    unsigned short* wb3 = wb2 + 2 * 4 * 64 * 8;    // 2*3*64*8 = 3072  (6 KB)
    int* deg       = (int*)(wb3 + 2 * 3 * 64 * 8);
    int* cursor    = deg + NNODES;
    int* row_start = cursor + NNODES;
    int* bsum      = row_start + NNODES + 2;
    int2* edges    = (int2*)(bsum + 64);           // 6.4 MB

    const int rowBlocks  = (NNODES + 63) / 64;     // 782
    const int nodeBlocks = (NNODES + 3) / 4;
    const int edgeBlocks = (NEDGES + 255) / 256;

    // ---- CSR build + weight conversion ----
    hipMemsetAsync(deg, 0, NNODES * sizeof(int), stream);
    convW_kernel<16, 4, 64, 64><<<16, 256, 0, stream>>>(W1, wb1);
    convW_kernel<2, 4, 64, 64><<<2, 256, 0, stream>>>(W2, wb2);
    convW_kernel<2, 3, 48, 40><<<2, 256, 0, stream>>>(W3, wb3);
    hist_kernel<<<edgeBlocks, 256, 0, stream>>>(row, deg);
    scan1_kernel<<<SCAN_BLOCKS, 256, 0, stream>>>(deg, row_start, bsum);
    scan2_kernel<<<1, 64, 0, stream>>>(bsum);
    scan3_kernel<<<(NNODES + 255) / 256, 256, 0, stream>>>(row_start, bsum, cursor);
    scatter_kernel<<<edgeBlocks, 256, 0, stream>>>(row, col, ew, cursor, edges);

    // ---- Layer 1 ----
    gemm1_mfma_kernel<<<rowBlocks, 256, 0, stream>>>(x, wb1, b1, Ab);
    spmm_bf64_kernel<true><<<nodeBlocks, 256, 0, stream>>>(Ab, edges, row_start, Bb);

    // ---- Layer 2 ----
    gemm_h_mfma_kernel<4, 64><<<rowBlocks, 256, 0, stream>>>(Bb, wb2, b2, Ab);
    spmm_bf64_kernel<false><<<nodeBlocks, 256, 0, stream>>>(Ab, edges, row_start, Bb);

    // ---- Layer 3 + fused log_softmax ----
    gemm_h_mfma_kernel<3, 40><<<rowBlocks, 256, 0, stream>>>(Bb, wb3, b3, Cb);
    spmm_bf40_lsm_kernel<<<nodeBlocks, 256, 0, stream>>>(Cb, edges, row_start, out);
}